// Round 13
// baseline (1552.870 us; speedup 1.0000x reference)
//
#include <hip/hip_runtime.h>
#include <hip/hip_bf16.h>
#include <type_traits>

typedef int  i32x4  __attribute__((ext_vector_type(4)));
typedef int  i32x16 __attribute__((ext_vector_type(16)));
typedef unsigned int uint;
typedef unsigned long long u64;

constexpr int TN = 64;
constexpr float W_INV  = 1.1920928955078125e-7f;   // 2^-23 (W1/W2 scale)
constexpr float WO_INV = 5.9604644775390625e-8f;   // 2^-24 (Wout scale)

// ---------------- ws layout (~27 MB) ----------------
static constexpr size_t OFF_XP2 = (size_t)16 << 20;
static constexpr size_t OFF_W1  = (size_t)24 << 20;
static constexpr size_t OFF_W2  = OFF_W1 + (size_t)3 * 4 * 16 * 8192;
static constexpr size_t OFF_WO  = OFF_W2 + (size_t)3 * 4 * 8 * 8192;
static constexpr size_t WS_NEED = OFF_WO + (size_t)3 * 512 * 512;

// ---------------- P0: bit-transpose-pack X  -> XP[b][kb][t] (u64) ----------------
__global__ __launch_bounds__(256) void pack_x(const float* __restrict__ X,
                                              u64* __restrict__ XP) {
    __shared__ float L[64 * 65];
    const int kw = blockIdx.x;   // 0..15 (kb)
    const int b  = blockIdx.y;   // 0..2047
    const int tid = threadIdx.x;
    const float* src = X + (((size_t)b * 1024 + kw * 64) << 6);
#pragma unroll
    for (int i = 0; i < 4; ++i) {
        int flat = tid + i * 256;
        float4 v = ((const float4*)src)[flat];
        int e0 = flat * 4;
        int k = e0 >> 6, t0 = e0 & 63;
        float* d = &L[k * 65 + t0];
        d[0] = v.x; d[1] = v.y; d[2] = v.z; d[3] = v.w;
    }
    __syncthreads();
    const int w = tid >> 6, lane = tid & 63;
    u64 myw = 0;
#pragma unroll
    for (int tt = 0; tt < 16; ++tt) {
        int t = w * 16 + tt;
        bool pred = L[lane * 65 + t] > 0.5f;   // lane indexes k
        u64 bm = __ballot(pred);
        if (lane == tt) myw = bm;
    }
    if (lane < 16) XP[((size_t)b * 16 + kw) * 64 + w * 16 + lane] = myw;
}

// ---------------- P1: quantize W (scale 2^23), 3-digit base-128, row-major tiles ----------------
// plane d: [hg(4)][kb(KB)] 8KB tiles of [128 row][64 k] i8
__global__ __launch_bounds__(256) void pack_w3(const float* __restrict__ W, int kshift, int KB,
                                               char* __restrict__ dAll) {
    int g = blockIdx.x * 256 + threadIdx.x;
    int h = g >> kshift;
    int k = g & ((1 << kshift) - 1);
    float v = W[g];
    int q  = (int)rintf(v * 8388608.f);
    int lo = ((q + 64) & 127) - 64;
    int q1 = (q - lo) >> 7;
    int mid = ((q1 + 64) & 127) - 64;
    int hi  = (q1 - mid) >> 7;
    size_t tile0 = (size_t)((h >> 7) * KB + (k >> 6)) * 8192;
    size_t inT   = (size_t)(h & 127) * 64 + (k & 63);
    size_t compStride = (size_t)4 * KB * 8192;
    dAll[tile0 + inT]                  = (char)hi;
    dAll[compStride + tile0 + inT]     = (char)mid;
    dAll[2 * compStride + tile0 + inT] = (char)lo;
}

// ---------------- P2: quantize Wout (scale 2^24), 3-digit, plain [d][o][h] ----------------
__global__ __launch_bounds__(256) void pack_wout3(const float* __restrict__ W,
                                                  char* __restrict__ dAll) {
    int g = blockIdx.x * 256 + threadIdx.x;   // 262144
    float v = W[g];
    int q  = (int)rintf(v * 16777216.f);
    int lo = ((q + 64) & 127) - 64;
    int q1 = (q - lo) >> 7;
    int mid = ((q1 + 64) & 127) - 64;
    int hi  = (q1 - mid) >> 7;
    dAll[g]          = (char)hi;
    dAll[262144 + g] = (char)mid;
    dAll[524288 + g] = (char)lo;
}

// ---------------- main fused i8 32x32 MFMA GEMM + LIF scan (v8: A+B prefetch) ----------------
// 256 thr = 4 waves = wm(4: 32h strip). Block 128h x 128n (2 batches), grid (1024, 4).
// Wave: 32h x 128n x 3 digits = 24 MFMA/K-step, barrier-free, reg-only K-loop.
// v8: BOTH A and B have a 1-step register prefetch so no load latency sits on the
// MFMA critical path (the rotation wait lands after ~880 cyc of MFMA issue).
template <int KB, bool EMIT>
__global__ __launch_bounds__(256, 2) void spike_mfma_v8(
    const char* __restrict__ dAll,   // [3][4 hg][KB][128][64]
    const void* __restrict__ XPsrc,
    const float* __restrict__ bias,  // [512]
    uint* __restrict__ XPdst,        // EMIT: u32 [b][16 kw][64 t]
    char* __restrict__ AccOut)       // !EMIT: i8 [b][512]
{
    __shared__ float LS[4][2][2048];   // 64 KB exactly
    const int tid = threadIdx.x;
    const int nb = blockIdx.x, hg = blockIdx.y;
    const int b0 = nb * 2;
    const int w = tid >> 6, lane = tid & 63;
    const int wm = w;
    const int l31 = lane & 31, lh = lane >> 5;

    i32x16 acc[3][4] = {};   // [digit][ni], ni = batch*2 + t-half

    const size_t dStride = (size_t)4 * KB * 8192;
    const char* aBase = dAll + (size_t)hg * KB * 8192 + (wm * 32 + l31) * 64 + lh * 16;

    const u64*  xp64a = (const u64*)XPsrc + (size_t)b0 * KB * 64 + l31;
    const u64*  xp64b = xp64a + (size_t)KB * 64;
    const uint* xp32a = (const uint*)XPsrc + (size_t)b0 * 1024 + l31;
    const uint* xp32b = xp32a + 1024;

    u64  b64C[4] = {}, b64N[4] = {};
    uint b32C[8] = {}, b32N[8] = {};
    i32x4 aC[3][2], aN[3][2];

    auto loadB = [&](int kb, u64 (&d64)[4], uint (&d32)[8]) {
        if constexpr (EMIT) {
            d64[0] = xp64a[(size_t)kb * 64];
            d64[1] = xp64a[(size_t)kb * 64 + 32];
            d64[2] = xp64b[(size_t)kb * 64];
            d64[3] = xp64b[(size_t)kb * 64 + 32];
        } else {
#pragma unroll
            for (int th = 0; th < 2; ++th)
#pragma unroll
                for (int ks = 0; ks < 2; ++ks) {
                    d32[(th    ) * 2 + ks] = xp32a[(size_t)(kb * 2 + ks) * 64 + th * 32];
                    d32[(2 + th) * 2 + ks] = xp32b[(size_t)(kb * 2 + ks) * 64 + th * 32];
                }
        }
    };
    auto loadA = [&](int kb, i32x4 (&dst)[3][2]) {
#pragma unroll
        for (int ks = 0; ks < 2; ++ks)
#pragma unroll
            for (int d = 0; d < 3; ++d)
                dst[d][ks] = *(const i32x4*)(aBase + d * dStride + (size_t)kb * 8192 + ks * 32);
    };

    loadA(0, aC);
    loadB(0, b64C, b32C);

    for (int kb = 0; kb < KB; ++kb) {
        if (kb + 1 < KB) {   // issue next-step loads BEFORE compute; wait hides under MFMA
            loadA(kb + 1, aN);
            loadB(kb + 1, b64N, b32N);
        }
        __builtin_amdgcn_s_setprio(1);
#pragma unroll
        for (int ks = 0; ks < 2; ++ks)
#pragma unroll
            for (int ni = 0; ni < 4; ++ni) {
                uint f;
                if constexpr (EMIT)
                    f = (uint)(b64C[ni] >> (ks * 32 + lh * 16)) & 0xFFFFu;
                else
                    f = (b32C[ni * 2 + ks] >> (lh * 16)) & 0xFFFFu;
                i32x4 bf;
                bf[0] = (int)((((f      ) & 15u) * 0x204081u) & 0x01010101u);
                bf[1] = (int)((((f >>  4) & 15u) * 0x204081u) & 0x01010101u);
                bf[2] = (int)((((f >>  8) & 15u) * 0x204081u) & 0x01010101u);
                bf[3] = (int)((((f >> 12) & 15u) * 0x204081u) & 0x01010101u);
#pragma unroll
                for (int d = 0; d < 3; ++d)
                    acc[d][ni] = __builtin_amdgcn_mfma_i32_32x32x32_i8(
                        aC[d][ks], bf, acc[d][ni], 0, 0, 0);
            }
        __builtin_amdgcn_s_setprio(0);
#pragma unroll
        for (int d = 0; d < 3; ++d) { aC[d][0] = aN[d][0]; aC[d][1] = aN[d][1]; }
#pragma unroll
        for (int i = 0; i < 4; ++i) b64C[i] = b64N[i];
#pragma unroll
        for (int i = 0; i < 8; ++i) b32C[i] = b32N[i];
    }

    // ---- epilogue: single staging pass, dual-batch concurrent scan ----
    float* slab = &LS[w][0][0];
#pragma unroll
    for (int ni = 0; ni < 4; ++ni) {
        const int bi = ni >> 1, th = ni & 1;
        const int t = th * 32 + l31;
        float* sb = slab + bi * 2048;
#pragma unroll
        for (int q = 0; q < 4; ++q)
#pragma unroll
            for (int j = 0; j < 4; ++j) {
                int r = q * 4 + j;
                int comb = (acc[0][ni][r] << 14) + (acc[1][ni][r] << 7) + acc[2][ni][r];
                int col = q * 8 + lh * 4 + j;
                sb[t * 32 + (col ^ (t & 31))] = (float)comb * W_INV;
            }
    }
    asm volatile("s_waitcnt lgkmcnt(0)" ::: "memory");
    __builtin_amdgcn_sched_barrier(0);
    {
        const int bi = lane >> 5;                 // lanes 0-31: batch0, 32-63: batch1
        const float bb = bias[hg * 128 + wm * 32 + l31];
        const float* sb = slab + bi * 2048;
        float v = 0.f, s = 0.f;
        uint w0 = 0, w1 = 0;
        int asum = 0;
        for (int tt = 0; tt < TN; ++tt) {
            float cc = sb[tt * 32 + (l31 ^ (tt & 31))] + bb;
            v = v * (1.f - s) * 0.75f + cc;
            bool sp = v > 0.5f;
            s = sp ? 1.f : 0.f;
            if constexpr (EMIT) {
                u64 bm = __ballot(sp);
                uint half = (lane < 32) ? (uint)bm : (uint)(bm >> 32);
                if (l31 == (tt & 31)) { if (tt < 32) w0 = half; else w1 = half; }
            } else {
                asum += sp ? 1 : 0;
            }
        }
        if constexpr (EMIT) {
            uint base = ((uint)(b0 + bi) * 16 + hg * 4 + wm) * 64;
            XPdst[base + l31] = w0;
            XPdst[base + 32 + l31] = w1;
        } else {
            AccOut[(size_t)(b0 + bi) * 512 + hg * 128 + wm * 32 + l31] = (char)asum;
        }
    }
}

// ---------------- K3: out = ACC @ Wout^T + bout via i8 MFMA ----------------
__global__ __launch_bounds__(256) void k3_i8(
    const char* __restrict__ dW,    // [3][512 o][512 h]
    const char* __restrict__ ACCb,  // [2048][512] i8
    const float* __restrict__ bq,   // [512]
    float* __restrict__ out)        // [2048][512]
{
    const int tid = threadIdx.x;
    const int w = tid >> 6, lane = tid & 63;
    const int l31 = lane & 31, lh = lane >> 5;
    const int bBlk = blockIdx.x * 64;
    const int oBase = blockIdx.y * 128 + w * 32;

    i32x16 acc[2][3] = {};
    const char* aP = dW + (size_t)(oBase + l31) * 512 + lh * 16;
    const char* bP = ACCb + (size_t)(bBlk + l31) * 512 + lh * 16;

#pragma unroll 4
    for (int ks = 0; ks < 16; ++ks) {
        i32x4 af[3], bf[2];
#pragma unroll
        for (int d = 0; d < 3; ++d)
            af[d] = *(const i32x4*)(aP + (size_t)d * 262144 + ks * 32);
#pragma unroll
        for (int bi = 0; bi < 2; ++bi)
            bf[bi] = *(const i32x4*)(bP + (size_t)bi * 32 * 512 + ks * 32);
#pragma unroll
        for (int bi = 0; bi < 2; ++bi)
#pragma unroll
            for (int d = 0; d < 3; ++d)
                acc[bi][d] = __builtin_amdgcn_mfma_i32_32x32x32_i8(af[d], bf[bi], acc[bi][d], 0, 0, 0);
    }
#pragma unroll
    for (int bi = 0; bi < 2; ++bi) {
        const size_t b = bBlk + bi * 32 + l31;
#pragma unroll
        for (int q = 0; q < 4; ++q) {
            const int oo = oBase + q * 8 + lh * 4;
            float4 bb = *(const float4*)&bq[oo];
            float4 o4;
#pragma unroll
            for (int j = 0; j < 4; ++j) {
                int r = q * 4 + j;
                float dv = (float)acc[bi][0][r] * 16384.f
                         + (float)acc[bi][1][r] * 128.f
                         + (float)acc[bi][2][r];
                ((float*)&o4)[j] = dv * WO_INV + ((const float*)&bb)[j];
            }
            *(float4*)&out[b * 512 + oo] = o4;
        }
    }
}

// ---------------- fallback f32 path (ws too small) ----------------
template <int KDIM, bool PIN>
__global__ __launch_bounds__(256) void gemm_scan(
    const float* __restrict__ Xf, const u64* __restrict__ Xp,
    const float* __restrict__ W, const float* __restrict__ bias,
    u64* __restrict__ Sout, float* __restrict__ AccOut) {
    __shared__ union {
        struct { float Wt[32 * 260]; float Xc[32 * 64]; } s;
        float C[256 * 64];
    } lds;
    const int b = blockIdx.y;
    const int h0 = blockIdx.x * 256;
    const int tid = threadIdx.x;
    const int tc = tid & 3, tr = tid >> 2;
    const int t0 = tc * 16, r0 = tr * 4;
    float c[4][16];
#pragma unroll
    for (int i = 0; i < 4; ++i)
#pragma unroll
        for (int j = 0; j < 16; ++j) c[i][j] = 0.f;
    for (int k0 = 0; k0 < KDIM; k0 += 32) {
        if constexpr (!PIN) {
            const float4* xsrc = (const float4*)(Xf + ((size_t)b * KDIM + k0) * 64);
            float4* xdst = (float4*)lds.s.Xc;
            xdst[tid] = xsrc[tid];
            xdst[tid + 256] = xsrc[tid + 256];
        } else {
            const int row = tid >> 3;
            const int bofs = (tid & 7) * 8;
            u64 m = Xp[(size_t)b * KDIM + k0 + row];
            float* xd = &lds.s.Xc[row * 64 + bofs];
#pragma unroll
            for (int q = 0; q < 8; ++q) xd[q] = (float)((m >> (bofs + q)) & 1ull);
        }
#pragma unroll
        for (int i = 0; i < 8; ++i) {
            int g = tid + 256 * i;
            int row = g >> 3, c4 = g & 7;
            float4 w4 = *(const float4*)(W + (size_t)(h0 + row) * KDIM + k0 + c4 * 4);
            lds.s.Wt[(c4 * 4 + 0) * 260 + row] = w4.x;
            lds.s.Wt[(c4 * 4 + 1) * 260 + row] = w4.y;
            lds.s.Wt[(c4 * 4 + 2) * 260 + row] = w4.z;
            lds.s.Wt[(c4 * 4 + 3) * 260 + row] = w4.w;
        }
        __syncthreads();
#pragma unroll 4
        for (int kk = 0; kk < 32; ++kk) {
            float4 wv = *(const float4*)&lds.s.Wt[kk * 260 + r0];
            const float4* xr = (const float4*)&lds.s.Xc[kk * 64 + t0];
            float4 x0 = xr[0], x1 = xr[1], x2 = xr[2], x3 = xr[3];
            float wr[4] = {wv.x, wv.y, wv.z, wv.w};
            float xs[16] = {x0.x, x0.y, x0.z, x0.w, x1.x, x1.y, x1.z, x1.w,
                            x2.x, x2.y, x2.z, x2.w, x3.x, x3.y, x3.z, x3.w};
#pragma unroll
            for (int i = 0; i < 4; ++i)
#pragma unroll
                for (int j = 0; j < 16; ++j) c[i][j] = fmaf(wr[i], xs[j], c[i][j]);
        }
        __syncthreads();
    }
#pragma unroll
    for (int i = 0; i < 4; ++i)
#pragma unroll
        for (int j4 = 0; j4 < 4; ++j4)
            *(float4*)&lds.C[(r0 + i) * 64 + t0 + j4 * 4] =
                make_float4(c[i][j4 * 4], c[i][j4 * 4 + 1], c[i][j4 * 4 + 2], c[i][j4 * 4 + 3]);
    __syncthreads();
    const float bb = bias[h0 + tid];
    float v = 0.f, s = 0.f;
    if constexpr (!PIN) {
        u64 m = 0;
#pragma unroll
        for (int t = 0; t < TN; ++t) {
            float cc = lds.C[tid * 64 + t] + bb;
            v = v * (1.f - s) * 0.75f + cc;
            bool sp = v > 0.5f;
            s = sp ? 1.f : 0.f;
            if (sp) m |= (1ull << t);
        }
        Sout[(size_t)b * 512 + h0 + tid] = m;
    } else {
        float acc = 0.f;
#pragma unroll
        for (int t = 0; t < TN; ++t) {
            float cc = lds.C[tid * 64 + t] + bb;
            v = v * (1.f - s) * 0.75f + cc;
            bool sp = v > 0.5f;
            s = sp ? 1.f : 0.f;
            acc += s;
        }
        AccOut[(size_t)b * 512 + h0 + tid] = acc;
    }
}

__global__ __launch_bounds__(256) void k3_f32(
    const float* __restrict__ A, const float* __restrict__ Wo,
    const float* __restrict__ bq, float* __restrict__ C) {
    __shared__ float Al[64][33];
    __shared__ float Bl[32][65];
    const int n0 = blockIdx.x * 64;
    const int m0 = blockIdx.y * 64;
    const int tid = threadIdx.x;
    const int c0 = (tid & 15) * 4;
    const int r0 = (tid >> 4) * 4;
    float acc[4][4];
#pragma unroll
    for (int i = 0; i < 4; ++i)
#pragma unroll
        for (int j = 0; j < 4; ++j) acc[i][j] = 0.f;
    for (int k0 = 0; k0 < 512; k0 += 32) {
#pragma unroll
        for (int i = 0; i < 2; ++i) {
            int g = tid + 256 * i;
            int row = g >> 3, c4 = g & 7;
            float4 v = *(const float4*)(A + (size_t)(m0 + row) * 512 + k0 + c4 * 4);
            float* d = &Al[row][c4 * 4];
            d[0] = v.x; d[1] = v.y; d[2] = v.z; d[3] = v.w;
        }
#pragma unroll
        for (int i = 0; i < 2; ++i) {
            int g = tid + 256 * i;
            int row = g >> 3, c4 = g & 7;
            float4 v = *(const float4*)(Wo + (size_t)(n0 + row) * 512 + k0 + c4 * 4);
            Bl[c4 * 4 + 0][row] = v.x; Bl[c4 * 4 + 1][row] = v.y;
            Bl[c4 * 4 + 2][row] = v.z; Bl[c4 * 4 + 3][row] = v.w;
        }
        __syncthreads();
#pragma unroll 8
        for (int kk = 0; kk < 32; ++kk) {
            float a0 = Al[r0 + 0][kk], a1 = Al[r0 + 1][kk];
            float a2 = Al[r0 + 2][kk], a3 = Al[r0 + 3][kk];
            float b0 = Bl[kk][c0 + 0], b1 = Bl[kk][c0 + 1];
            float b2 = Bl[kk][c0 + 2], b3 = Bl[kk][c0 + 3];
            acc[0][0] = fmaf(a0, b0, acc[0][0]); acc[0][1] = fmaf(a0, b1, acc[0][1]);
            acc[0][2] = fmaf(a0, b2, acc[0][2]); acc[0][3] = fmaf(a0, b3, acc[0][3]);
            acc[1][0] = fmaf(a1, b0, acc[1][0]); acc[1][1] = fmaf(a1, b1, acc[1][1]);
            acc[1][2] = fmaf(a1, b2, acc[1][2]); acc[1][3] = fmaf(a1, b3, acc[1][3]);
            acc[2][0] = fmaf(a2, b0, acc[2][0]); acc[2][1] = fmaf(a2, b1, acc[2][1]);
            acc[2][2] = fmaf(a2, b2, acc[2][2]); acc[2][3] = fmaf(a2, b3, acc[2][3]);
            acc[3][0] = fmaf(a3, b0, acc[3][0]); acc[3][1] = fmaf(a3, b1, acc[3][1]);
            acc[3][2] = fmaf(a3, b2, acc[3][2]); acc[3][3] = fmaf(a3, b3, acc[3][3]);
        }
        __syncthreads();
    }
#pragma unroll
    for (int i = 0; i < 4; ++i) {
        float4 o = make_float4(acc[i][0] + bq[n0 + c0 + 0], acc[i][1] + bq[n0 + c0 + 1],
                               acc[i][2] + bq[n0 + c0 + 2], acc[i][3] + bq[n0 + c0 + 3]);
        *(float4*)&C[(size_t)(m0 + r0 + i) * 512 + n0 + c0] = o;
    }
}

extern "C" void kernel_launch(void* const* d_in, const int* in_sizes, int n_in,
                              void* d_out, int out_size, void* d_ws, size_t ws_size,
                              hipStream_t stream) {
    const float* X  = (const float*)d_in[0];
    const float* W1 = (const float*)d_in[1];
    const float* b1 = (const float*)d_in[2];
    const float* W2 = (const float*)d_in[3];
    const float* b2 = (const float*)d_in[4];
    const float* Wo = (const float*)d_in[5];
    const float* bo = (const float*)d_in[6];
    float* out = (float*)d_out;

    if (ws_size >= WS_NEED) {
        char* ws = (char*)d_ws;
        u64* XPk1 = (u64*)ws;
        uint* XP2 = (uint*)(ws + OFF_XP2);
        char* W1d = ws + OFF_W1;
        char* W2d = ws + OFF_W2;
        char* WoD = ws + OFF_WO;
        char* ACCb = ws;   // aliases XPk1 (dead after K1)

        pack_x<<<dim3(16, 2048), 256, 0, stream>>>(X, XPk1);
        pack_w3<<<dim3(2048), 256, 0, stream>>>(W1, 10, 16, W1d);
        pack_w3<<<dim3(1024), 256, 0, stream>>>(W2, 9, 8, W2d);
        pack_wout3<<<dim3(1024), 256, 0, stream>>>(Wo, WoD);
        spike_mfma_v8<16, true><<<dim3(1024, 4), 256, 0, stream>>>(W1d, XPk1, b1, XP2, nullptr);
        spike_mfma_v8<8, false><<<dim3(1024, 4), 256, 0, stream>>>(W2d, XP2, b2, nullptr, ACCb);
        k3_i8<<<dim3(32, 4), 256, 0, stream>>>(WoD, ACCb, bo, out);
    } else {
        u64* S1 = (u64*)d_ws;
        float* ACC = (float*)((char*)d_ws + (size_t)2048 * 512 * 8);
        gemm_scan<1024, false><<<dim3(2, 2048), 256, 0, stream>>>(X, nullptr, W1, b1, S1, nullptr);
        gemm_scan<512, true><<<dim3(2, 2048), 256, 0, stream>>>(nullptr, S1, W2, b2, nullptr, ACC);
        k3_f32<<<dim3(8, 32), 256, 0, stream>>>(ACC, Wo, bo, out);
    }
}

// Round 14
// 379.884 us; speedup vs baseline: 4.0877x; 4.0877x over previous
//
#include <hip/hip_runtime.h>
#include <hip/hip_bf16.h>
#include <type_traits>

typedef int  i32x4  __attribute__((ext_vector_type(4)));
typedef int  i32x16 __attribute__((ext_vector_type(16)));
typedef unsigned int uint;
typedef unsigned long long u64;

constexpr int TN = 64;
constexpr float W_INV  = 1.1920928955078125e-7f;   // 2^-23 (W1/W2 scale)
constexpr float WO_INV = 5.9604644775390625e-8f;   // 2^-24 (Wout scale)

// ---------------- ws layout (~27 MB) ----------------
// [0,16M)   XPk1 u64 [2048 b][16 kb][64 t]   (ACCb i8 [2048][512] aliases after K1)
// [16M,24M) XP2  u32 [2048 b][16 kw][64 t]
// [24M,...] W1 digits [3][4 hg][16 kb][128 row][64 k] i8
//           W2 digits [3][4][8][128][64] i8
//           Wout digits [3][512 o][512 h] i8
static constexpr size_t OFF_XP2 = (size_t)16 << 20;
static constexpr size_t OFF_W1  = (size_t)24 << 20;
static constexpr size_t OFF_W2  = OFF_W1 + (size_t)3 * 4 * 16 * 8192;
static constexpr size_t OFF_WO  = OFF_W2 + (size_t)3 * 4 * 8 * 8192;
static constexpr size_t WS_NEED = OFF_WO + (size_t)3 * 512 * 512;

// ---------------- P0: bit-transpose-pack X  -> XP[b][kb][t] (u64) ----------------
__global__ __launch_bounds__(256) void pack_x(const float* __restrict__ X,
                                              u64* __restrict__ XP) {
    __shared__ float L[64 * 65];
    const int kw = blockIdx.x;   // 0..15 (kb)
    const int b  = blockIdx.y;   // 0..2047
    const int tid = threadIdx.x;
    const float* src = X + (((size_t)b * 1024 + kw * 64) << 6);
#pragma unroll
    for (int i = 0; i < 4; ++i) {
        int flat = tid + i * 256;
        float4 v = ((const float4*)src)[flat];
        int e0 = flat * 4;
        int k = e0 >> 6, t0 = e0 & 63;
        float* d = &L[k * 65 + t0];
        d[0] = v.x; d[1] = v.y; d[2] = v.z; d[3] = v.w;
    }
    __syncthreads();
    const int w = tid >> 6, lane = tid & 63;
    u64 myw = 0;
#pragma unroll
    for (int tt = 0; tt < 16; ++tt) {
        int t = w * 16 + tt;
        bool pred = L[lane * 65 + t] > 0.5f;   // lane indexes k
        u64 bm = __ballot(pred);
        if (lane == tt) myw = bm;
    }
    if (lane < 16) XP[((size_t)b * 16 + kw) * 64 + w * 16 + lane] = myw;
}

// ---------------- P1 (fused): quantize W1, W2 (2^23) and Wout (2^24) in one launch ----------------
// W1/W2 layout: plane d: [hg(4)][kb(KB)] 8KB tiles of [128 row][64 k] i8
// Wout layout: [d][o][h] plain
__device__ __forceinline__ void qsplit(float v, float scale, int& hi, int& mid, int& lo) {
    int q  = (int)rintf(v * scale);
    lo = ((q + 64) & 127) - 64;
    int q1 = (q - lo) >> 7;
    mid = ((q1 + 64) & 127) - 64;
    hi  = (q1 - mid) >> 7;
}

__global__ __launch_bounds__(256) void pack_all(const float* __restrict__ W1,
                                                const float* __restrict__ W2,
                                                const float* __restrict__ Wo,
                                                char* __restrict__ W1d,
                                                char* __restrict__ W2d,
                                                char* __restrict__ WoD) {
    int blk = blockIdx.x;
    int tid = threadIdx.x;
    if (blk < 2048) {                        // W1: 524288 elems, kshift=10, KB=16
        int g = blk * 256 + tid;
        int h = g >> 10, k = g & 1023;
        int hi, mid, lo;
        qsplit(W1[g], 8388608.f, hi, mid, lo);
        size_t tile0 = (size_t)((h >> 7) * 16 + (k >> 6)) * 8192;
        size_t inT   = (size_t)(h & 127) * 64 + (k & 63);
        size_t cs = (size_t)4 * 16 * 8192;
        W1d[tile0 + inT]          = (char)hi;
        W1d[cs + tile0 + inT]     = (char)mid;
        W1d[2 * cs + tile0 + inT] = (char)lo;
    } else if (blk < 3072) {                 // W2: 262144 elems, kshift=9, KB=8
        int g = (blk - 2048) * 256 + tid;
        int h = g >> 9, k = g & 511;
        int hi, mid, lo;
        qsplit(W2[g], 8388608.f, hi, mid, lo);
        size_t tile0 = (size_t)((h >> 7) * 8 + (k >> 6)) * 8192;
        size_t inT   = (size_t)(h & 127) * 64 + (k & 63);
        size_t cs = (size_t)4 * 8 * 8192;
        W2d[tile0 + inT]          = (char)hi;
        W2d[cs + tile0 + inT]     = (char)mid;
        W2d[2 * cs + tile0 + inT] = (char)lo;
    } else {                                 // Wout: 262144 elems, scale 2^24
        int g = (blk - 3072) * 256 + tid;
        int hi, mid, lo;
        qsplit(Wo[g], 16777216.f, hi, mid, lo);
        WoD[g]          = (char)hi;
        WoD[262144 + g] = (char)mid;
        WoD[524288 + g] = (char)lo;
    }
}

// ---------------- main fused i8 32x32 MFMA GEMM + LIF scan (v7 — proven) ----------------
// 256 thr = 4 waves = wm(4: 32h strip). Block 128h x 128n (2 batches), grid (1024, 4).
// Wave: 32h x 128n x 3 digits = 24 MFMA/K-step, barrier-free, reg-only K-loop.
// A loaded transiently at point of use (REGISTER-BUDGET-CRITICAL: persistent A-prefetch
// spills the 192-reg accumulator at launch_bounds(256,2) — R13 regression, do not re-add).
// Epilogue: dual-batch concurrent scan; per-wave slab [2][64t][32h], XOR swizzle col^(t&31).
template <int KB, bool EMIT>
__global__ __launch_bounds__(256, 2) void spike_mfma_v7(
    const char* __restrict__ dAll,   // [3][4 hg][KB][128][64]
    const void* __restrict__ XPsrc,
    const float* __restrict__ bias,  // [512]
    uint* __restrict__ XPdst,        // EMIT: u32 [b][16 kw][64 t]
    char* __restrict__ AccOut)       // !EMIT: i8 [b][512]
{
    __shared__ float LS[4][2][2048];   // 64 KB exactly
    const int tid = threadIdx.x;
    const int nb = blockIdx.x, hg = blockIdx.y;
    const int b0 = nb * 2;
    const int w = tid >> 6, lane = tid & 63;
    const int wm = w;
    const int l31 = lane & 31, lh = lane >> 5;

    i32x16 acc[3][4] = {};   // [digit][ni], ni = batch*2 + t-half

    const size_t dStride = (size_t)4 * KB * 8192;
    const char* aBase = dAll + (size_t)hg * KB * 8192 + (wm * 32 + l31) * 64 + lh * 16;

    const u64*  xp64a = (const u64*)XPsrc + (size_t)b0 * KB * 64 + l31;
    const u64*  xp64b = xp64a + (size_t)KB * 64;
    const uint* xp32a = (const uint*)XPsrc + (size_t)b0 * 1024 + l31;
    const uint* xp32b = xp32a + 1024;

    u64  b64C[4] = {}, b64N[4] = {};
    uint b32C[8] = {}, b32N[8] = {};

    auto loadB = [&](int kb, u64 (&d64)[4], uint (&d32)[8]) {
        if constexpr (EMIT) {
            d64[0] = xp64a[(size_t)kb * 64];
            d64[1] = xp64a[(size_t)kb * 64 + 32];
            d64[2] = xp64b[(size_t)kb * 64];
            d64[3] = xp64b[(size_t)kb * 64 + 32];
        } else {
#pragma unroll
            for (int th = 0; th < 2; ++th)
#pragma unroll
                for (int ks = 0; ks < 2; ++ks) {
                    d32[(th    ) * 2 + ks] = xp32a[(size_t)(kb * 2 + ks) * 64 + th * 32];
                    d32[(2 + th) * 2 + ks] = xp32b[(size_t)(kb * 2 + ks) * 64 + th * 32];
                }
        }
    };

    loadB(0, b64C, b32C);

    for (int kb = 0; kb < KB; ++kb) {
        // A fragments, issued ks-major: first 12 MFMAs depend only on the first 3 loads
        i32x4 af[3][2];
#pragma unroll
        for (int ks = 0; ks < 2; ++ks)
#pragma unroll
            for (int d = 0; d < 3; ++d)
                af[d][ks] = *(const i32x4*)(aBase + d * dStride + (size_t)kb * 8192 + ks * 32);
        if (kb + 1 < KB) loadB(kb + 1, b64N, b32N);
        __builtin_amdgcn_s_setprio(1);
#pragma unroll
        for (int ks = 0; ks < 2; ++ks)
#pragma unroll
            for (int ni = 0; ni < 4; ++ni) {
                uint f;
                if constexpr (EMIT)
                    f = (uint)(b64C[ni] >> (ks * 32 + lh * 16)) & 0xFFFFu;
                else
                    f = (b32C[ni * 2 + ks] >> (lh * 16)) & 0xFFFFu;
                i32x4 bf;
                bf[0] = (int)((((f      ) & 15u) * 0x204081u) & 0x01010101u);
                bf[1] = (int)((((f >>  4) & 15u) * 0x204081u) & 0x01010101u);
                bf[2] = (int)((((f >>  8) & 15u) * 0x204081u) & 0x01010101u);
                bf[3] = (int)((((f >> 12) & 15u) * 0x204081u) & 0x01010101u);
#pragma unroll
                for (int d = 0; d < 3; ++d)
                    acc[d][ni] = __builtin_amdgcn_mfma_i32_32x32x32_i8(
                        af[d][ks], bf, acc[d][ni], 0, 0, 0);
            }
        __builtin_amdgcn_s_setprio(0);
#pragma unroll
        for (int i = 0; i < 4; ++i) b64C[i] = b64N[i];
#pragma unroll
        for (int i = 0; i < 8; ++i) b32C[i] = b32N[i];
    }

    // ---- epilogue: single staging pass, dual-batch concurrent scan ----
    float* slab = &LS[w][0][0];
#pragma unroll
    for (int ni = 0; ni < 4; ++ni) {
        const int bi = ni >> 1, th = ni & 1;
        const int t = th * 32 + l31;
        float* sb = slab + bi * 2048;
#pragma unroll
        for (int q = 0; q < 4; ++q)
#pragma unroll
            for (int j = 0; j < 4; ++j) {
                int r = q * 4 + j;
                int comb = (acc[0][ni][r] << 14) + (acc[1][ni][r] << 7) + acc[2][ni][r];
                int col = q * 8 + lh * 4 + j;
                sb[t * 32 + (col ^ (t & 31))] = (float)comb * W_INV;
            }
    }
    asm volatile("s_waitcnt lgkmcnt(0)" ::: "memory");
    __builtin_amdgcn_sched_barrier(0);
    {
        const int bi = lane >> 5;                 // lanes 0-31: batch0, 32-63: batch1
        const float bb = bias[hg * 128 + wm * 32 + l31];
        const float* sb = slab + bi * 2048;
        float v = 0.f, s = 0.f;
        uint w0 = 0, w1 = 0;
        int asum = 0;
        for (int tt = 0; tt < TN; ++tt) {
            float cc = sb[tt * 32 + (l31 ^ (tt & 31))] + bb;
            v = v * (1.f - s) * 0.75f + cc;
            bool sp = v > 0.5f;
            s = sp ? 1.f : 0.f;
            if constexpr (EMIT) {
                u64 bm = __ballot(sp);
                uint half = (lane < 32) ? (uint)bm : (uint)(bm >> 32);
                if (l31 == (tt & 31)) { if (tt < 32) w0 = half; else w1 = half; }
            } else {
                asum += sp ? 1 : 0;
            }
        }
        if constexpr (EMIT) {
            uint base = ((uint)(b0 + bi) * 16 + hg * 4 + wm) * 64;
            XPdst[base + l31] = w0;
            XPdst[base + 32 + l31] = w1;
        } else {
            AccOut[(size_t)(b0 + bi) * 512 + hg * 128 + wm * 32 + l31] = (char)asum;
        }
    }
}

// ---------------- K3: out = ACC @ Wout^T + bout via i8 MFMA ----------------
__global__ __launch_bounds__(256) void k3_i8(
    const char* __restrict__ dW,    // [3][512 o][512 h]
    const char* __restrict__ ACCb,  // [2048][512] i8
    const float* __restrict__ bq,   // [512]
    float* __restrict__ out)        // [2048][512]
{
    const int tid = threadIdx.x;
    const int w = tid >> 6, lane = tid & 63;
    const int l31 = lane & 31, lh = lane >> 5;
    const int bBlk = blockIdx.x * 64;
    const int oBase = blockIdx.y * 128 + w * 32;

    i32x16 acc[2][3] = {};
    const char* aP = dW + (size_t)(oBase + l31) * 512 + lh * 16;
    const char* bP = ACCb + (size_t)(bBlk + l31) * 512 + lh * 16;

#pragma unroll 4
    for (int ks = 0; ks < 16; ++ks) {
        i32x4 af[3], bf[2];
#pragma unroll
        for (int d = 0; d < 3; ++d)
            af[d] = *(const i32x4*)(aP + (size_t)d * 262144 + ks * 32);
#pragma unroll
        for (int bi = 0; bi < 2; ++bi)
            bf[bi] = *(const i32x4*)(bP + (size_t)bi * 32 * 512 + ks * 32);
#pragma unroll
        for (int bi = 0; bi < 2; ++bi)
#pragma unroll
            for (int d = 0; d < 3; ++d)
                acc[bi][d] = __builtin_amdgcn_mfma_i32_32x32x32_i8(af[d], bf[bi], acc[bi][d], 0, 0, 0);
    }
#pragma unroll
    for (int bi = 0; bi < 2; ++bi) {
        const size_t b = bBlk + bi * 32 + l31;
#pragma unroll
        for (int q = 0; q < 4; ++q) {
            const int oo = oBase + q * 8 + lh * 4;
            float4 bb = *(const float4*)&bq[oo];
            float4 o4;
#pragma unroll
            for (int j = 0; j < 4; ++j) {
                int r = q * 4 + j;
                float dv = (float)acc[bi][0][r] * 16384.f
                         + (float)acc[bi][1][r] * 128.f
                         + (float)acc[bi][2][r];
                ((float*)&o4)[j] = dv * WO_INV + ((const float*)&bb)[j];
            }
            *(float4*)&out[b * 512 + oo] = o4;
        }
    }
}

// ---------------- fallback f32 path (ws too small) ----------------
template <int KDIM, bool PIN>
__global__ __launch_bounds__(256) void gemm_scan(
    const float* __restrict__ Xf, const u64* __restrict__ Xp,
    const float* __restrict__ W, const float* __restrict__ bias,
    u64* __restrict__ Sout, float* __restrict__ AccOut) {
    __shared__ union {
        struct { float Wt[32 * 260]; float Xc[32 * 64]; } s;
        float C[256 * 64];
    } lds;
    const int b = blockIdx.y;
    const int h0 = blockIdx.x * 256;
    const int tid = threadIdx.x;
    const int tc = tid & 3, tr = tid >> 2;
    const int t0 = tc * 16, r0 = tr * 4;
    float c[4][16];
#pragma unroll
    for (int i = 0; i < 4; ++i)
#pragma unroll
        for (int j = 0; j < 16; ++j) c[i][j] = 0.f;
    for (int k0 = 0; k0 < KDIM; k0 += 32) {
        if constexpr (!PIN) {
            const float4* xsrc = (const float4*)(Xf + ((size_t)b * KDIM + k0) * 64);
            float4* xdst = (float4*)lds.s.Xc;
            xdst[tid] = xsrc[tid];
            xdst[tid + 256] = xsrc[tid + 256];
        } else {
            const int row = tid >> 3;
            const int bofs = (tid & 7) * 8;
            u64 m = Xp[(size_t)b * KDIM + k0 + row];
            float* xd = &lds.s.Xc[row * 64 + bofs];
#pragma unroll
            for (int q = 0; q < 8; ++q) xd[q] = (float)((m >> (bofs + q)) & 1ull);
        }
#pragma unroll
        for (int i = 0; i < 8; ++i) {
            int g = tid + 256 * i;
            int row = g >> 3, c4 = g & 7;
            float4 w4 = *(const float4*)(W + (size_t)(h0 + row) * KDIM + k0 + c4 * 4);
            lds.s.Wt[(c4 * 4 + 0) * 260 + row] = w4.x;
            lds.s.Wt[(c4 * 4 + 1) * 260 + row] = w4.y;
            lds.s.Wt[(c4 * 4 + 2) * 260 + row] = w4.z;
            lds.s.Wt[(c4 * 4 + 3) * 260 + row] = w4.w;
        }
        __syncthreads();
#pragma unroll 4
        for (int kk = 0; kk < 32; ++kk) {
            float4 wv = *(const float4*)&lds.s.Wt[kk * 260 + r0];
            const float4* xr = (const float4*)&lds.s.Xc[kk * 64 + t0];
            float4 x0 = xr[0], x1 = xr[1], x2 = xr[2], x3 = xr[3];
            float wr[4] = {wv.x, wv.y, wv.z, wv.w};
            float xs[16] = {x0.x, x0.y, x0.z, x0.w, x1.x, x1.y, x1.z, x1.w,
                            x2.x, x2.y, x2.z, x2.w, x3.x, x3.y, x3.z, x3.w};
#pragma unroll
            for (int i = 0; i < 4; ++i)
#pragma unroll
                for (int j = 0; j < 16; ++j) c[i][j] = fmaf(wr[i], xs[j], c[i][j]);
        }
        __syncthreads();
    }
#pragma unroll
    for (int i = 0; i < 4; ++i)
#pragma unroll
        for (int j4 = 0; j4 < 4; ++j4)
            *(float4*)&lds.C[(r0 + i) * 64 + t0 + j4 * 4] =
                make_float4(c[i][j4 * 4], c[i][j4 * 4 + 1], c[i][j4 * 4 + 2], c[i][j4 * 4 + 3]);
    __syncthreads();
    const float bb = bias[h0 + tid];
    float v = 0.f, s = 0.f;
    if constexpr (!PIN) {
        u64 m = 0;
#pragma unroll
        for (int t = 0; t < TN; ++t) {
            float cc = lds.C[tid * 64 + t] + bb;
            v = v * (1.f - s) * 0.75f + cc;
            bool sp = v > 0.5f;
            s = sp ? 1.f : 0.f;
            if (sp) m |= (1ull << t);
        }
        Sout[(size_t)b * 512 + h0 + tid] = m;
    } else {
        float acc = 0.f;
#pragma unroll
        for (int t = 0; t < TN; ++t) {
            float cc = lds.C[tid * 64 + t] + bb;
            v = v * (1.f - s) * 0.75f + cc;
            bool sp = v > 0.5f;
            s = sp ? 1.f : 0.f;
            acc += s;
        }
        AccOut[(size_t)b * 512 + h0 + tid] = acc;
    }
}

__global__ __launch_bounds__(256) void k3_f32(
    const float* __restrict__ A, const float* __restrict__ Wo,
    const float* __restrict__ bq, float* __restrict__ C) {
    __shared__ float Al[64][33];
    __shared__ float Bl[32][65];
    const int n0 = blockIdx.x * 64;
    const int m0 = blockIdx.y * 64;
    const int tid = threadIdx.x;
    const int c0 = (tid & 15) * 4;
    const int r0 = (tid >> 4) * 4;
    float acc[4][4];
#pragma unroll
    for (int i = 0; i < 4; ++i)
#pragma unroll
        for (int j = 0; j < 4; ++j) acc[i][j] = 0.f;
    for (int k0 = 0; k0 < 512; k0 += 32) {
#pragma unroll
        for (int i = 0; i < 2; ++i) {
            int g = tid + 256 * i;
            int row = g >> 3, c4 = g & 7;
            float4 v = *(const float4*)(A + (size_t)(m0 + row) * 512 + k0 + c4 * 4);
            float* d = &Al[row][c4 * 4];
            d[0] = v.x; d[1] = v.y; d[2] = v.z; d[3] = v.w;
        }
#pragma unroll
        for (int i = 0; i < 2; ++i) {
            int g = tid + 256 * i;
            int row = g >> 3, c4 = g & 7;
            float4 v = *(const float4*)(Wo + (size_t)(n0 + row) * 512 + k0 + c4 * 4);
            Bl[c4 * 4 + 0][row] = v.x; Bl[c4 * 4 + 1][row] = v.y;
            Bl[c4 * 4 + 2][row] = v.z; Bl[c4 * 4 + 3][row] = v.w;
        }
        __syncthreads();
#pragma unroll 8
        for (int kk = 0; kk < 32; ++kk) {
            float a0 = Al[r0 + 0][kk], a1 = Al[r0 + 1][kk];
            float a2 = Al[r0 + 2][kk], a3 = Al[r0 + 3][kk];
            float b0 = Bl[kk][c0 + 0], b1 = Bl[kk][c0 + 1];
            float b2 = Bl[kk][c0 + 2], b3 = Bl[kk][c0 + 3];
            acc[0][0] = fmaf(a0, b0, acc[0][0]); acc[0][1] = fmaf(a0, b1, acc[0][1]);
            acc[0][2] = fmaf(a0, b2, acc[0][2]); acc[0][3] = fmaf(a0, b3, acc[0][3]);
            acc[1][0] = fmaf(a1, b0, acc[1][0]); acc[1][1] = fmaf(a1, b1, acc[1][1]);
            acc[1][2] = fmaf(a1, b2, acc[1][2]); acc[1][3] = fmaf(a1, b3, acc[1][3]);
            acc[2][0] = fmaf(a2, b0, acc[2][0]); acc[2][1] = fmaf(a2, b1, acc[2][1]);
            acc[2][2] = fmaf(a2, b2, acc[2][2]); acc[2][3] = fmaf(a2, b3, acc[2][3]);
            acc[3][0] = fmaf(a3, b0, acc[3][0]); acc[3][1] = fmaf(a3, b1, acc[3][1]);
            acc[3][2] = fmaf(a3, b2, acc[3][2]); acc[3][3] = fmaf(a3, b3, acc[3][3]);
        }
        __syncthreads();
    }
#pragma unroll
    for (int i = 0; i < 4; ++i) {
        float4 o = make_float4(acc[i][0] + bq[n0 + c0 + 0], acc[i][1] + bq[n0 + c0 + 1],
                               acc[i][2] + bq[n0 + c0 + 2], acc[i][3] + bq[n0 + c0 + 3]);
        *(float4*)&C[(size_t)(m0 + r0 + i) * 512 + n0 + c0] = o;
    }
}

extern "C" void kernel_launch(void* const* d_in, const int* in_sizes, int n_in,
                              void* d_out, int out_size, void* d_ws, size_t ws_size,
                              hipStream_t stream) {
    const float* X  = (const float*)d_in[0];
    const float* W1 = (const float*)d_in[1];
    const float* b1 = (const float*)d_in[2];
    const float* W2 = (const float*)d_in[3];
    const float* b2 = (const float*)d_in[4];
    const float* Wo = (const float*)d_in[5];
    const float* bo = (const float*)d_in[6];
    float* out = (float*)d_out;

    if (ws_size >= WS_NEED) {
        char* ws = (char*)d_ws;
        u64* XPk1 = (u64*)ws;
        uint* XP2 = (uint*)(ws + OFF_XP2);
        char* W1d = ws + OFF_W1;
        char* W2d = ws + OFF_W2;
        char* WoD = ws + OFF_WO;
        char* ACCb = ws;   // aliases XPk1 (dead after K1)

        pack_x<<<dim3(16, 2048), 256, 0, stream>>>(X, XPk1);
        pack_all<<<dim3(4096), 256, 0, stream>>>(W1, W2, Wo, W1d, W2d, WoD);
        spike_mfma_v7<16, true><<<dim3(1024, 4), 256, 0, stream>>>(W1d, XPk1, b1, XP2, nullptr);
        spike_mfma_v7<8, false><<<dim3(1024, 4), 256, 0, stream>>>(W2d, XP2, b2, nullptr, ACCb);
        k3_i8<<<dim3(32, 4), 256, 0, stream>>>(WoD, ACCb, bo, out);
    } else {
        u64* S1 = (u64*)d_ws;
        float* ACC = (float*)((char*)d_ws + (size_t)2048 * 512 * 8);
        gemm_scan<1024, false><<<dim3(2, 2048), 256, 0, stream>>>(X, nullptr, W1, b1, S1, nullptr);
        gemm_scan<512, true><<<dim3(2, 2048), 256, 0, stream>>>(nullptr, S1, W2, b2, nullptr, ACC);
        k3_f32<<<dim3(8, 32), 256, 0, stream>>>(ACC, Wo, bo, out);
    }
}